// Round 1
// baseline (471.462 us; speedup 1.0000x reference)
//
#include <hip/hip_runtime.h>
#include <cstdint>

#define IN_F 4096
#define OUT_F 11008
#define NG 32           // groups along K (group size 128)
#define BM 64
#define BN 128
#define BK 64
#define LDA 72          // padded LDS row stride in halfs (64 + 8) -> 144 B
#define NKT (IN_F / BK) // 64 K-tiles

typedef _Float16 half8 __attribute__((ext_vector_type(8)));
typedef float f32x4 __attribute__((ext_vector_type(4)));

__global__ __launch_bounds__(256) void qlin_mfma(
    const float* __restrict__ x, const int* __restrict__ qw,
    const float* __restrict__ sc, const float* __restrict__ zpt,
    const float* __restrict__ bias, float* __restrict__ out)
{
    // LDS tiles, 16B-aligned so ds_read_b128 is legal
    __shared__ __align__(16) _Float16 As[BM * LDA]; //  9216 B
    __shared__ __align__(16) _Float16 Bs[BN * LDA]; // 18432 B

    const int tid = threadIdx.x;
    const int m0 = blockIdx.x * BM;   // x-major over M so concurrent blocks share B tiles
    const int n0 = blockIdx.y * BN;

    const int lane = tid & 63;
    const int w    = tid >> 6;
    const int wm   = (w & 1) * 32;    // wave's m-offset in tile
    const int wn   = (w >> 1) * 64;   // wave's n-offset in tile
    const int l16  = lane & 15;
    const int quad = lane >> 4;

    const int srow = tid >> 4;        // staging: 16 threads per row-slice
    const int sc4  = tid & 15;        // 4-element chunk index within row

    // prefetch registers for next K-tile
    float4 aP[4];
    int4   bP[8];
    float  sP[8], zP[8];

    auto prefetch = [&](int kt) {
        const int k0 = kt * BK;
        const int g  = k0 >> 7;       // quant group (BK=64 divides 128)
#pragma unroll
        for (int it = 0; it < 4; ++it) {
            int row = it * 16 + srow;
            aP[it] = *(const float4*)(x + (size_t)(m0 + row) * IN_F + k0 + sc4 * 4);
        }
#pragma unroll
        for (int it = 0; it < 8; ++it) {
            int row = it * 16 + srow;
            bP[it] = *(const int4*)(qw + (size_t)(n0 + row) * IN_F + k0 + sc4 * 4);
            sP[it] = sc [(size_t)(n0 + row) * NG + g];
            zP[it] = zpt[(size_t)(n0 + row) * NG + g];
        }
    };

    auto stage = [&]() {
        // A: fp32 -> f16 (packed RTZ), 8B LDS writes
#pragma unroll
        for (int it = 0; it < 4; ++it) {
            int row = it * 16 + srow;
            auto h0 = __builtin_amdgcn_cvt_pkrtz(aP[it].x, aP[it].y);
            auto h1 = __builtin_amdgcn_cvt_pkrtz(aP[it].z, aP[it].w);
            uint32_t* p = (uint32_t*)&As[row * LDA + sc4 * 4];
            p[0] = __builtin_bit_cast(uint32_t, h0);
            p[1] = __builtin_bit_cast(uint32_t, h1);
        }
        // B: dequant (q - zp) * s = q*s + (-zp*s), then pack to f16
#pragma unroll
        for (int it = 0; it < 8; ++it) {
            int row = it * 16 + srow;
            float s  = sP[it];
            float bb = -zP[it] * s;
            float f0 = (float)bP[it].x * s + bb;
            float f1 = (float)bP[it].y * s + bb;
            float f2 = (float)bP[it].z * s + bb;
            float f3 = (float)bP[it].w * s + bb;
            auto h0 = __builtin_amdgcn_cvt_pkrtz(f0, f1);
            auto h1 = __builtin_amdgcn_cvt_pkrtz(f2, f3);
            uint32_t* p = (uint32_t*)&Bs[row * LDA + sc4 * 4];
            p[0] = __builtin_bit_cast(uint32_t, h0);
            p[1] = __builtin_bit_cast(uint32_t, h1);
        }
    };

    f32x4 acc[2][4];
#pragma unroll
    for (int mt = 0; mt < 2; ++mt)
#pragma unroll
        for (int nt = 0; nt < 4; ++nt)
            acc[mt][nt] = (f32x4){0.f, 0.f, 0.f, 0.f};

    auto compute = [&]() {
#pragma unroll
        for (int ks = 0; ks < 2; ++ks) {
            half8 a[2], b[4];
#pragma unroll
            for (int mt = 0; mt < 2; ++mt)
                a[mt] = *(const half8*)&As[(wm + mt * 16 + l16) * LDA + ks * 32 + quad * 8];
#pragma unroll
            for (int nt = 0; nt < 4; ++nt)
                b[nt] = *(const half8*)&Bs[(wn + nt * 16 + l16) * LDA + ks * 32 + quad * 8];
#pragma unroll
            for (int mt = 0; mt < 2; ++mt)
#pragma unroll
                for (int nt = 0; nt < 4; ++nt)
                    acc[mt][nt] = __builtin_amdgcn_mfma_f32_16x16x32_f16(
                        a[mt], b[nt], acc[mt][nt], 0, 0, 0);
        }
    };

    prefetch(0);
    stage();
    __syncthreads();

#pragma unroll 1
    for (int kt = 0; kt < NKT; ++kt) {
        const bool more = (kt + 1) < NKT;
        if (more) prefetch(kt + 1);   // global loads in flight over compute
        compute();                     // LDS -> frags -> 16 MFMAs/wave
        __syncthreads();               // all waves done reading LDS
        if (more) { stage(); __syncthreads(); }
    }

    // Epilogue: C/D layout col = lane&15, row = quad*4 + reg
#pragma unroll
    for (int nt = 0; nt < 4; ++nt) {
        int n = n0 + wn + nt * 16 + l16;
        float bv = bias[n];
#pragma unroll
        for (int mt = 0; mt < 2; ++mt) {
            int mb = m0 + wm + mt * 16 + quad * 4;
#pragma unroll
            for (int r = 0; r < 4; ++r)
                out[(size_t)(mb + r) * OUT_F + n] = acc[mt][nt][r] + bv;
        }
    }
}

extern "C" void kernel_launch(void* const* d_in, const int* in_sizes, int n_in,
                              void* d_out, int out_size, void* d_ws, size_t ws_size,
                              hipStream_t stream) {
    const float* x    = (const float*)d_in[0];
    const int*   qw   = (const int*)d_in[1];
    const float* scp  = (const float*)d_in[2];
    const float* zpp  = (const float*)d_in[3];
    const float* bias = (const float*)d_in[4];
    float* out = (float*)d_out;
    (void)in_sizes; (void)n_in; (void)out_size; (void)d_ws; (void)ws_size;

    dim3 grid(512 / BM, OUT_F / BN);  // (8, 86) = 688 blocks
    qlin_mfma<<<grid, dim3(256), 0, stream>>>(x, qw, scp, zpp, bias, out);
}